// Round 7
// baseline (713.251 us; speedup 1.0000x reference)
//
#include <hip/hip_runtime.h>
#include <hip/hip_bf16.h>
#include <math.h>

// NeRF coarse renderer, fused MFMA implementation with split-bf16 trunk.
// I/O dtype: FLOAT32. Density path (W1,W2,W3,sigma) runs in hi+lo split-bf16
// (~fp22 effective); rgb branch (Wfeat,Wdir,rgb) enters linearly -> bf16.
// Round 9 (3rd submit -- rounds 5,6 failed on GPU acquisition, no data):
// depth-1 weight double-buffering, corrected codegen. Round 8's
// lambda-with-array-reference version defeated SROA (allocas stayed in
// scratch: WRITE_SIZE 416KB->639MB, dur 595us). Same schedule now expressed
// as macros over named arrays with compile-time indices only -- the pattern
// that kept R7's fragments in registers (VGPR=52, zero scratch).
// Schedule: load W(s+1) -> MFMA(s) -> load W(s+2) -> MFMA(s+1); weight-load
// latency hides under the MFMA cluster via counted vmcnt. Acts (ah/al)
// single-buffered from LDS (TLP-covered). Per-acc MFMA order unchanged
// (hh,hl,lh per s) -> bit-identical output.
// Block = 1 ray = 64 sample-points (LDS rows); 2 blocks/CU (72 KB LDS).

typedef unsigned short u16;
typedef unsigned int   u32;
typedef __bf16 bf16x8 __attribute__((ext_vector_type(8)));
typedef float  f32x4  __attribute__((ext_vector_type(4)));

#define HI_STRIDE 296   // u16 elems; 592B rows -> conflict-free b128 (20i%32 pattern)
#define LO_STRIDE 264   // u16 elems; 528B rows -> conflict-free b128 (4i%32 pattern)
#define NROW 64

// Repacked weights (MFMA A-operand fragments):
// hi: W1(16384) W2(65536) W3(65536) Wfeat(65536) Wdir(36864)
// lo: W1(16384) W2(65536) W3(65536)   (residuals, trunk only)
__device__ __align__(16) u16 g_whi[249856];
__device__ __align__(16) u16 g_wlo[147456];

constexpr int OFF_W1 = 0;
constexpr int OFF_W2 = 16384;
constexpr int OFF_W3 = 81920;
constexpr int OFF_WF = 147456;
constexpr int OFF_WD = 212992;

static __device__ __forceinline__ float bf2f(u16 u) {
  return __uint_as_float(((u32)u) << 16);
}
static __device__ __forceinline__ u16 f2bf(float f) {   // RNE (repack kernel only)
  u32 x = __float_as_uint(f);
  return (u16)((x + 0x7FFFu + ((x >> 16) & 1u)) >> 16);
}
// Packed f32x2 -> bf16x2 (RNE). dst.lo16 = bf(a), dst.hi16 = bf(b).
static __device__ __forceinline__ u32 cvt_pk_bf16(float a, float b) {
  u32 r;
  asm("v_cvt_pk_bf16_f32 %0, %1, %2" : "=v"(r) : "v"(a), "v"(b));
  return r;
}
static __device__ __forceinline__ float wash(float x) { // NaN -> 0
  return (x == x) ? x : 0.0f;
}

struct alignas(8) U16x4 { u16 x, y, z, w; };

// ---------------------------------------------------------------------------
// Weight repack (f32 -> bf16 hi, + bf16 lo residual for W1..W3) into
// A-operand fragments of mfma_f32_16x16x32_bf16 (A := W^T tile):
// element pos = lane*8 + j of fragment (t,s) holds
//   W[s*32 + (lane>>4)*8 + j][t*16 + (lane&15)]   (zero-padded for k >= K).
// One pass: e < 249856; trunk range also emits the lo residual.
// ---------------------------------------------------------------------------
__global__ void repack_kernel(const float* __restrict__ w1, const float* __restrict__ w2,
                              const float* __restrict__ w3, const float* __restrict__ wf,
                              const float* __restrict__ wd) {
  int e = blockIdx.x * 256 + threadIdx.x;
  const float* src; int K, N, ks, base;
  if (e < 81920)       { if (e < 16384) { src = w1; K = 63;  N = 256; ks = 2; base = OFF_W1; }
                         else           { src = w2; K = 256; N = 256; ks = 8; base = OFF_W2; } }
  else if (e < 147456) { src = w3; K = 256; N = 256; ks = 8; base = OFF_W3; }
  else if (e < 212992) { src = wf; K = 256; N = 256; ks = 8; base = OFF_WF; }
  else                 { src = wd; K = 283; N = 128; ks = 9; base = OFF_WD; }
  int le   = e - base;
  int f    = le >> 9, pos = le & 511;
  int lane = pos >> 3, j = pos & 7;
  int t    = f / ks,  s = f - t * ks;
  int k    = s * 32 + ((lane >> 4) << 3) + j;
  int n    = (t << 4) + (lane & 15);
  float v  = (k < K) ? src[k * N + n] : 0.0f;
  u16 h    = f2bf(v);
  g_whi[e] = h;
  if (e < 147456) g_wlo[e] = f2bf(v - bf2f(h));   // trunk residual plane
}

// ---------------------------------------------------------------------------
// One dense layer on the shared activation buffer, in place.
// 8 waves = 2 row-groups (rg) x 4 col-groups (cg). Wave computes RT row-tiles
// x NT col-tiles. SPLIT: acc += Wh*Ah + Wh*Al + Wl*Ah (fp32 accumulate);
// writeback stores hi + lo residual planes (packed cvt).
// Weight fragments double-buffered in named register arrays via macros
// (compile-time indices only -- SROA-safe, no lambdas / array references).
// ---------------------------------------------------------------------------
template<int KS, int NT, int RT, bool RELU, bool SPLIT>
static __device__ __forceinline__ void mlp_layer(u16* hi, u16* lo,
                                                 const u16* __restrict__ wh_,
                                                 const u16* __restrict__ wl_,
                                                 const float* __restrict__ bias,
                                                 int rg, int cg, int lane) {
  f32x4 acc[RT][NT];
#pragma unroll
  for (int rt = 0; rt < RT; ++rt)
#pragma unroll
    for (int nt = 0; nt < NT; ++nt) {
      f32x4 z = {0.0f, 0.0f, 0.0f, 0.0f};
      acc[rt][nt] = z;
    }
  const int l15 = lane & 15, q = lane >> 4;

  bf16x8 whA[NT], wlA[NT], whB[NT], wlB[NT];

#define LOADW_M(WH, WL, S)                                                    \
  {                                                                           \
    _Pragma("unroll")                                                         \
    for (int nt = 0; nt < NT; ++nt) {                                         \
      const int t = cg * NT + nt;                                             \
      WH[nt] = *reinterpret_cast<const bf16x8*>(                              \
          &wh_[(t * KS + (S)) * 512 + lane * 8]);                             \
      if constexpr (SPLIT)                                                    \
        WL[nt] = *reinterpret_cast<const bf16x8*>(                            \
            &wl_[(t * KS + (S)) * 512 + lane * 8]);                           \
    }                                                                         \
  }

#define STEP_M(WH, WL, S)                                                     \
  {                                                                           \
    bf16x8 ah[RT], al[RT];                                                    \
    _Pragma("unroll")                                                         \
    for (int rt = 0; rt < RT; ++rt) {                                         \
      const int row = (rg * RT + rt) * 16 + l15;                              \
      ah[rt] = *reinterpret_cast<const bf16x8*>(                              \
          &hi[row * HI_STRIDE + (S) * 32 + q * 8]);                           \
      if constexpr (SPLIT)                                                    \
        al[rt] = *reinterpret_cast<const bf16x8*>(                            \
            &lo[row * LO_STRIDE + (S) * 32 + q * 8]);                         \
    }                                                                         \
    _Pragma("unroll")                                                         \
    for (int nt = 0; nt < NT; ++nt)                                           \
      _Pragma("unroll")                                                       \
      for (int rt = 0; rt < RT; ++rt)                                         \
        acc[rt][nt] = __builtin_amdgcn_mfma_f32_16x16x32_bf16(                \
            WH[nt], ah[rt], acc[rt][nt], 0, 0, 0);                            \
    if constexpr (SPLIT) {                                                    \
      _Pragma("unroll")                                                       \
      for (int nt = 0; nt < NT; ++nt)                                         \
        _Pragma("unroll")                                                     \
        for (int rt = 0; rt < RT; ++rt)                                       \
          acc[rt][nt] = __builtin_amdgcn_mfma_f32_16x16x32_bf16(              \
              WH[nt], al[rt], acc[rt][nt], 0, 0, 0);                          \
      _Pragma("unroll")                                                       \
      for (int nt = 0; nt < NT; ++nt)                                         \
        _Pragma("unroll")                                                     \
        for (int rt = 0; rt < RT; ++rt)                                       \
          acc[rt][nt] = __builtin_amdgcn_mfma_f32_16x16x32_bf16(              \
              WL[nt], ah[rt], acc[rt][nt], 0, 0, 0);                          \
    }                                                                         \
  }

  LOADW_M(whA, wlA, 0)
#pragma unroll 1
  for (int s = 0; s + 1 < KS; s += 2) {
    LOADW_M(whB, wlB, s + 1)       // prefetch next step's weights
    STEP_M(whA, wlA, s)            // consume A while B's loads in flight
    if (s + 2 < KS) LOADW_M(whA, wlA, s + 2)
    STEP_M(whB, wlB, s + 1)
  }
  if constexpr ((KS & 1) != 0) STEP_M(whA, wlA, KS - 1)

#undef LOADW_M
#undef STEP_M

  __syncthreads();   // all reads of act complete before overwrite
#pragma unroll
  for (int nt = 0; nt < NT; ++nt) {
    const int nb = (cg * NT + nt) * 16 + q * 4;
    const float b0 = bias[nb + 0], b1 = bias[nb + 1];
    const float b2 = bias[nb + 2], b3 = bias[nb + 3];
#pragma unroll
    for (int rt = 0; rt < RT; ++rt) {
      const int row = (rg * RT + rt) * 16 + l15;
      float v0 = acc[rt][nt][0] + b0;
      float v1 = acc[rt][nt][1] + b1;
      float v2 = acc[rt][nt][2] + b2;
      float v3 = acc[rt][nt][3] + b3;
      if (RELU) {
        v0 = fmaxf(v0, 0.0f); v1 = fmaxf(v1, 0.0f);
        v2 = fmaxf(v2, 0.0f); v3 = fmaxf(v3, 0.0f);
      }
      u32 h01 = cvt_pk_bf16(v0, v1);
      u32 h23 = cvt_pk_bf16(v2, v3);
      *reinterpret_cast<uint2*>(&hi[row * HI_STRIDE + nb]) = make_uint2(h01, h23);
      if constexpr (SPLIT) {
        float l0 = v0 - __uint_as_float(h01 << 16);
        float l1 = v1 - __uint_as_float(h01 & 0xFFFF0000u);
        float l2 = v2 - __uint_as_float(h23 << 16);
        float l3 = v3 - __uint_as_float(h23 & 0xFFFF0000u);
        u32 lo01 = cvt_pk_bf16(l0, l1);
        u32 lo23 = cvt_pk_bf16(l2, l3);
        *reinterpret_cast<uint2*>(&lo[row * LO_STRIDE + nb]) = make_uint2(lo01, lo23);
      }
    }
  }
  __syncthreads();
}

// ---------------------------------------------------------------------------
// Main fused kernel. Block b = ray b; row = sample index (0..63); 512 threads.
// ---------------------------------------------------------------------------
__global__ __launch_bounds__(512, 4)
void nerf_kernel(const float* __restrict__ xyz, const float* __restrict__ vdirs,
                 const float* __restrict__ b1, const float* __restrict__ b2,
                 const float* __restrict__ b3, const float* __restrict__ wsig,
                 const float* __restrict__ bsig, const float* __restrict__ bfeat,
                 const float* __restrict__ bdir, const float* __restrict__ wrgb,
                 const float* __restrict__ brgb, float* __restrict__ out) {
  __shared__ u16  s_hi[NROW * HI_STRIDE];   // 37888 B
  __shared__ u16  s_lo[NROW * LO_STRIDE];   // 33792 B
  __shared__ float s_geo[6];                // xyz[3], normalized vd[3]
  __shared__ float s_de[32];                // dir posenc (27) + zero pad

  const int tid  = threadIdx.x;
  const int wave = tid >> 6;
  const int lane = tid & 63;
  const int rg   = wave >> 2;               // row-group 0..1
  const int cg   = wave & 3;                // col-group 0..3

  // --- Phase A1: ray geometry (1 thread) ---
  if (tid == 0) {
    int rgI = blockIdx.x;
    float vx = vdirs[rgI * 3 + 0];
    float vy = vdirs[rgI * 3 + 1];
    float vz = vdirs[rgI * 3 + 2];
    float inv = 1.0f / sqrtf(vx * vx + vy * vy + vz * vz + 1e-20f);
    s_geo[0] = xyz[rgI * 3 + 0];
    s_geo[1] = xyz[rgI * 3 + 1];
    s_geo[2] = xyz[rgI * 3 + 2];
    s_geo[3] = vx * inv;
    s_geo[4] = vy * inv;
    s_geo[5] = vz * inv;
  }
  __syncthreads();

  // --- Phase A2: direction posenc (32 threads), 27 feats + zero pad ---
  if (tid < 32) {
    float val = 0.0f;
    if (tid < 3) val = s_geo[3 + tid];
    else if (tid < 27) {
      int fi = tid - 3, l = fi / 6, m = fi % 6;
      int ii = (m < 3) ? m : m - 3;
      float ang = s_geo[3 + ii] * (float)(1 << l);
      val = (m < 3) ? sinf(ang) : cosf(ang);
    }
    s_de[tid] = val;
  }

  // --- Phase B: sample points + posenc(L=10) -> cols 0..63 (63 zero), split ---
  {
    int row = tid >> 3, c8 = tid & 7;
    float t  = (float)row * (1.0f / 63.0f);
    float ts = 2.0f * (1.0f - t) + 6.0f * t;
    float p[3];
    p[0] = s_geo[0] + ts * s_geo[3];
    p[1] = s_geo[1] + ts * s_geo[4];
    p[2] = s_geo[2] + ts * s_geo[5];
    float val[8];
#pragma unroll
    for (int j = 0; j < 8; ++j) {
      int f = c8 * 8 + j;
      if (f < 3) val[j] = p[f];
      else if (f == 63) val[j] = 0.0f;
      else {
        int fi = f - 3, l = fi / 6, m = fi % 6;
        int ii = (m < 3) ? m : m - 3;
        float ang = p[ii] * (float)(1 << l);
        val[j] = (m < 3) ? sinf(ang) : cosf(ang);
      }
    }
    u32* hp = reinterpret_cast<u32*>(&s_hi[row * HI_STRIDE + c8 * 8]);
    u32* lp = reinterpret_cast<u32*>(&s_lo[row * LO_STRIDE + c8 * 8]);
#pragma unroll
    for (int jp = 0; jp < 4; ++jp) {
      u32 h = cvt_pk_bf16(val[2 * jp], val[2 * jp + 1]);
      float l0 = val[2 * jp]     - __uint_as_float(h << 16);
      float l1 = val[2 * jp + 1] - __uint_as_float(h & 0xFFFF0000u);
      hp[jp] = h;
      lp[jp] = cvt_pk_bf16(l0, l1);
    }
  }
  __syncthreads();

  // --- MLP trunk (split precision) ---
  mlp_layer<2, 4, 2, true, true>(s_hi, s_lo, g_whi + OFF_W1, g_wlo + OFF_W1,
                                 b1, rg, cg, lane);   // 63(+1)->256
  mlp_layer<8, 4, 2, true, true>(s_hi, s_lo, g_whi + OFF_W2, g_wlo + OFF_W2,
                                 b2, rg, cg, lane);   // 256->256
  mlp_layer<8, 4, 2, true, true>(s_hi, s_lo, g_whi + OFF_W3, g_wlo + OFF_W3,
                                 b3, rg, cg, lane);   // 256->256

  // --- sigma head (fp32 weights, split h3): reads before feat writeback ---
  float my_den = 0.0f;
  if (tid < 64) {
    float a = 0.0f;
    const float4* wp = reinterpret_cast<const float4*>(wsig);
#pragma unroll 8
    for (int k4 = 0; k4 < 64; ++k4) {
      U16x4 h = *reinterpret_cast<const U16x4*>(&s_hi[tid * HI_STRIDE + k4 * 4]);
      U16x4 l = *reinterpret_cast<const U16x4*>(&s_lo[tid * LO_STRIDE + k4 * 4]);
      float4 w = wp[k4];
      a += (bf2f(h.x) + bf2f(l.x)) * w.x + (bf2f(h.y) + bf2f(l.y)) * w.y
         + (bf2f(h.z) + bf2f(l.z)) * w.z + (bf2f(h.w) + bf2f(l.w)) * w.w;
    }
    my_den = wash(a + bsig[0]);
  }
  // ordering safe: feat layer's internal __syncthreads precedes its writes

  mlp_layer<8, 4, 2, false, false>(s_hi, s_lo, g_whi + OFF_WF, g_wlo,
                                   bfeat, rg, cg, lane); // feat (bf16, no relu)

  // --- append direction encoding: cols 256..287 (283..287 zero via s_de pad) ---
  {
    int row = tid >> 3, i0 = (tid & 7) * 4;
    u32 d01 = cvt_pk_bf16(s_de[i0 + 0], s_de[i0 + 1]);
    u32 d23 = cvt_pk_bf16(s_de[i0 + 2], s_de[i0 + 3]);
    u32* dp = reinterpret_cast<u32*>(&s_hi[row * HI_STRIDE + 256 + i0]);
    dp[0] = d01; dp[1] = d23;
  }
  __syncthreads();

  mlp_layer<9, 2, 2, true, false>(s_hi, s_lo, g_whi + OFF_WD, g_wlo,
                                  bdir, rg, cg, lane);  // 283(+5)->128

  // --- rgb head (fp32 weights) ---
  float r0 = 0.0f, r1 = 0.0f, r2 = 0.0f;
  if (tid < 64) {
    float a0 = brgb[0], a1 = brgb[1], a2 = brgb[2];
#pragma unroll 8
    for (int k = 0; k < 128; ++k) {
      float hv = bf2f(s_hi[tid * HI_STRIDE + k]);
      a0 += hv * wrgb[k * 3 + 0];
      a1 += hv * wrgb[k * 3 + 1];
      a2 += hv * wrgb[k * 3 + 2];
    }
    a0 = wash(a0); a1 = wash(a1); a2 = wash(a2);
    r0 = 1.0f / (1.0f + expf(-a0));
    r1 = 1.0f / (1.0f + expf(-a1));
    r2 = 1.0f / (1.0f + expf(-a2));
  }

  // --- Phase D: volume render (wave 0; lane = sample) ---
  if (wave == 0) {
    int rgI = blockIdx.x;
    float t  = (float)lane * (1.0f / 63.0f);
    float ts = 2.0f * (1.0f - t) + 6.0f * t;
    float delta;
    if (lane < 63) {
      float t2 = (float)(lane + 1) * (1.0f / 63.0f);
      delta = (2.0f * (1.0f - t2) + 6.0f * t2) - ts;
    } else delta = 1e10f;
    float sig = fmaxf(my_den, 0.0f);
    float sd  = fminf(sig * delta, 60.0f);   // exp(-60)~1e-26: same semantics
    // exclusive prefix sum of sd across the 64-lane wave
    float incl = sd;
#pragma unroll
    for (int o = 1; o < 64; o <<= 1) {
      float v = __shfl_up(incl, o, 64);
      if (lane >= o) incl += v;
    }
    float excl  = fminf(fmaxf(incl - sd, 0.0f), 60.0f);
    float T     = expf(-excl);
    float alpha = 1.0f - expf(-sd);
    float w     = T * alpha;
    float sw = w, swr = w * r0, swg = w * r1, swb = w * r2, swd = w * ts;
#pragma unroll
    for (int o = 32; o > 0; o >>= 1) {
      sw  += __shfl_xor(sw,  o, 64);
      swr += __shfl_xor(swr, o, 64);
      swg += __shfl_xor(swg, o, 64);
      swb += __shfl_xor(swb, o, 64);
      swd += __shfl_xor(swd, o, 64);
    }
    if (lane == 0) {
      float bg = 1.0f - sw;               // white background
      out[rgI * 3 + 0]  = swr + bg;
      out[rgI * 3 + 1]  = swg + bg;
      out[rgI * 3 + 2]  = swb + bg;
      out[12288 + rgI]  = swd;            // depth_map
      out[16384 + rgI]  = sw;             // alpha_map
    }
  }
}

extern "C" void kernel_launch(void* const* d_in, const int* in_sizes, int n_in,
                              void* d_out, int out_size, void* d_ws, size_t ws_size,
                              hipStream_t stream) {
  const float* xyz   = (const float*)d_in[0];
  const float* vdirs = (const float*)d_in[1];
  const float* W1    = (const float*)d_in[2];
  const float* b1    = (const float*)d_in[3];
  const float* W2    = (const float*)d_in[4];
  const float* b2    = (const float*)d_in[5];
  const float* W3    = (const float*)d_in[6];
  const float* b3    = (const float*)d_in[7];
  const float* Wsig  = (const float*)d_in[8];
  const float* bsig  = (const float*)d_in[9];
  const float* Wfeat = (const float*)d_in[10];
  const float* bfeat = (const float*)d_in[11];
  const float* Wdir  = (const float*)d_in[12];
  const float* bdir  = (const float*)d_in[13];
  const float* Wrgb  = (const float*)d_in[14];
  const float* brgb  = (const float*)d_in[15];
  float* out = (float*)d_out;

  repack_kernel<<<dim3(976), dim3(256), 0, stream>>>(W1, W2, W3, Wfeat, Wdir);
  nerf_kernel<<<dim3(4096), dim3(512), 0, stream>>>(
      xyz, vdirs, b1, b2, b3, Wsig, bsig, bfeat, bdir, Wrgb, brgb, out);
}

// Round 10
// 367.011 us; speedup vs baseline: 1.9434x; 1.9434x over previous
//
#include <hip/hip_runtime.h>
#include <hip/hip_bf16.h>
#include <math.h>

// NeRF coarse renderer, fused MFMA implementation with split-bf16 trunk.
// I/O dtype: FLOAT32. Density path (W1,W2,W3,sigma) runs in hi+lo split-bf16
// (~fp22 effective); rgb branch (Wfeat,Wdir,rgb) enters linearly -> bf16.
// Round 10 (3rd submit -- rounds 8,9 failed on GPU acquisition, no data):
// abandon register double-buffering (R8 lambdas and R9 macros both
// left allocas in scratch -- arrays live across a runtime back-edge with
// conditional refill are not SROA-promotable; 600+MB spill traffic both
// times). Return to the R7-measured base (356us, VGPR 52, zero scratch) +
// two evidenced tweaks:
//  - k-loop fully unrolled (compile-time indices -> pure SSA; R0 A/B showed
//    full unroll ~1.5% faster than rolled, negligible 2.6B/thread spill).
//  - s_setprio(1) around each MFMA cluster (T5): 2 independent blocks/CU at
//    free-running phases = the phase-diverse regime where setprio measured
//    +4-7% (attn m191), not the lockstep-GEMM null (m190).
// Per-acc MFMA order unchanged (hh,hl,lh per s) -> bit-identical output.
// Block = 1 ray = 64 sample-points (LDS rows); 2 blocks/CU (72 KB LDS).

typedef unsigned short u16;
typedef unsigned int   u32;
typedef __bf16 bf16x8 __attribute__((ext_vector_type(8)));
typedef float  f32x4  __attribute__((ext_vector_type(4)));

#define HI_STRIDE 296   // u16 elems; 592B rows -> conflict-free b128 (20i%32 pattern)
#define LO_STRIDE 264   // u16 elems; 528B rows -> conflict-free b128 (4i%32 pattern)
#define NROW 64

// Repacked weights (MFMA A-operand fragments):
// hi: W1(16384) W2(65536) W3(65536) Wfeat(65536) Wdir(36864)
// lo: W1(16384) W2(65536) W3(65536)   (residuals, trunk only)
__device__ __align__(16) u16 g_whi[249856];
__device__ __align__(16) u16 g_wlo[147456];

constexpr int OFF_W1 = 0;
constexpr int OFF_W2 = 16384;
constexpr int OFF_W3 = 81920;
constexpr int OFF_WF = 147456;
constexpr int OFF_WD = 212992;

static __device__ __forceinline__ float bf2f(u16 u) {
  return __uint_as_float(((u32)u) << 16);
}
static __device__ __forceinline__ u16 f2bf(float f) {   // RNE (repack kernel only)
  u32 x = __float_as_uint(f);
  return (u16)((x + 0x7FFFu + ((x >> 16) & 1u)) >> 16);
}
// Packed f32x2 -> bf16x2 (RNE). dst.lo16 = bf(a), dst.hi16 = bf(b).
static __device__ __forceinline__ u32 cvt_pk_bf16(float a, float b) {
  u32 r;
  asm("v_cvt_pk_bf16_f32 %0, %1, %2" : "=v"(r) : "v"(a), "v"(b));
  return r;
}
static __device__ __forceinline__ float wash(float x) { // NaN -> 0
  return (x == x) ? x : 0.0f;
}

struct alignas(8) U16x4 { u16 x, y, z, w; };

// ---------------------------------------------------------------------------
// Weight repack (f32 -> bf16 hi, + bf16 lo residual for W1..W3) into
// A-operand fragments of mfma_f32_16x16x32_bf16 (A := W^T tile):
// element pos = lane*8 + j of fragment (t,s) holds
//   W[s*32 + (lane>>4)*8 + j][t*16 + (lane&15)]   (zero-padded for k >= K).
// One pass: e < 249856; trunk range also emits the lo residual.
// ---------------------------------------------------------------------------
__global__ void repack_kernel(const float* __restrict__ w1, const float* __restrict__ w2,
                              const float* __restrict__ w3, const float* __restrict__ wf,
                              const float* __restrict__ wd) {
  int e = blockIdx.x * 256 + threadIdx.x;
  const float* src; int K, N, ks, base;
  if (e < 81920)       { if (e < 16384) { src = w1; K = 63;  N = 256; ks = 2; base = OFF_W1; }
                         else           { src = w2; K = 256; N = 256; ks = 8; base = OFF_W2; } }
  else if (e < 147456) { src = w3; K = 256; N = 256; ks = 8; base = OFF_W3; }
  else if (e < 212992) { src = wf; K = 256; N = 256; ks = 8; base = OFF_WF; }
  else                 { src = wd; K = 283; N = 128; ks = 9; base = OFF_WD; }
  int le   = e - base;
  int f    = le >> 9, pos = le & 511;
  int lane = pos >> 3, j = pos & 7;
  int t    = f / ks,  s = f - t * ks;
  int k    = s * 32 + ((lane >> 4) << 3) + j;
  int n    = (t << 4) + (lane & 15);
  float v  = (k < K) ? src[k * N + n] : 0.0f;
  u16 h    = f2bf(v);
  g_whi[e] = h;
  if (e < 147456) g_wlo[e] = f2bf(v - bf2f(h));   // trunk residual plane
}

// ---------------------------------------------------------------------------
// One dense layer on the shared activation buffer, in place.
// 8 waves = 2 row-groups (rg) x 4 col-groups (cg). Wave computes RT row-tiles
// x NT col-tiles. SPLIT: acc += Wh*Ah + Wh*Al + Wl*Ah (fp32 accumulate);
// writeback stores hi + lo residual planes (packed cvt).
// k-loop fully unrolled (compile-time indices, SSA-clean); per k-step the
// fragments load then term-major MFMA (hh* then hl* then lh*) so consecutive
// MFMAs hit different acc tiles; setprio(1) keeps the matrix pipe fed while
// the other resident block issues memory ops.
// ---------------------------------------------------------------------------
template<int KS, int NT, int RT, bool RELU, bool SPLIT>
static __device__ __forceinline__ void mlp_layer(u16* hi, u16* lo,
                                                 const u16* __restrict__ wh_,
                                                 const u16* __restrict__ wl_,
                                                 const float* __restrict__ bias,
                                                 int rg, int cg, int lane) {
  f32x4 acc[RT][NT];
#pragma unroll
  for (int rt = 0; rt < RT; ++rt)
#pragma unroll
    for (int nt = 0; nt < NT; ++nt) {
      f32x4 z = {0.0f, 0.0f, 0.0f, 0.0f};
      acc[rt][nt] = z;
    }
  const int l15 = lane & 15, q = lane >> 4;
#pragma unroll
  for (int s = 0; s < KS; ++s) {
    bf16x8 ah[RT], al[RT];
#pragma unroll
    for (int rt = 0; rt < RT; ++rt) {
      const int row = (rg * RT + rt) * 16 + l15;
      ah[rt] = *reinterpret_cast<const bf16x8*>(&hi[row * HI_STRIDE + s * 32 + q * 8]);
      if (SPLIT)
        al[rt] = *reinterpret_cast<const bf16x8*>(&lo[row * LO_STRIDE + s * 32 + q * 8]);
    }
    bf16x8 wh[NT], wl[NT];
#pragma unroll
    for (int nt = 0; nt < NT; ++nt) {
      const int t = cg * NT + nt;
      wh[nt] = *reinterpret_cast<const bf16x8*>(&wh_[(t * KS + s) * 512 + lane * 8]);
      if (SPLIT)
        wl[nt] = *reinterpret_cast<const bf16x8*>(&wl_[(t * KS + s) * 512 + lane * 8]);
    }
    __builtin_amdgcn_s_setprio(1);
    // term hh: Wh * Ah (all tiles)
#pragma unroll
    for (int nt = 0; nt < NT; ++nt)
#pragma unroll
      for (int rt = 0; rt < RT; ++rt)
        acc[rt][nt] = __builtin_amdgcn_mfma_f32_16x16x32_bf16(
            wh[nt], ah[rt], acc[rt][nt], 0, 0, 0);
    if (SPLIT) {
      // term hl: Wh * Al
#pragma unroll
      for (int nt = 0; nt < NT; ++nt)
#pragma unroll
        for (int rt = 0; rt < RT; ++rt)
          acc[rt][nt] = __builtin_amdgcn_mfma_f32_16x16x32_bf16(
              wh[nt], al[rt], acc[rt][nt], 0, 0, 0);
      // term lh: Wl * Ah
#pragma unroll
      for (int nt = 0; nt < NT; ++nt)
#pragma unroll
        for (int rt = 0; rt < RT; ++rt)
          acc[rt][nt] = __builtin_amdgcn_mfma_f32_16x16x32_bf16(
              wl[nt], ah[rt], acc[rt][nt], 0, 0, 0);
    }
    __builtin_amdgcn_s_setprio(0);
  }
  __syncthreads();   // all reads of act complete before overwrite
#pragma unroll
  for (int nt = 0; nt < NT; ++nt) {
    const int nb = (cg * NT + nt) * 16 + q * 4;
    const float b0 = bias[nb + 0], b1 = bias[nb + 1];
    const float b2 = bias[nb + 2], b3 = bias[nb + 3];
#pragma unroll
    for (int rt = 0; rt < RT; ++rt) {
      const int row = (rg * RT + rt) * 16 + l15;
      float v0 = acc[rt][nt][0] + b0;
      float v1 = acc[rt][nt][1] + b1;
      float v2 = acc[rt][nt][2] + b2;
      float v3 = acc[rt][nt][3] + b3;
      if (RELU) {
        v0 = fmaxf(v0, 0.0f); v1 = fmaxf(v1, 0.0f);
        v2 = fmaxf(v2, 0.0f); v3 = fmaxf(v3, 0.0f);
      }
      u32 h01 = cvt_pk_bf16(v0, v1);
      u32 h23 = cvt_pk_bf16(v2, v3);
      *reinterpret_cast<uint2*>(&hi[row * HI_STRIDE + nb]) = make_uint2(h01, h23);
      if (SPLIT) {
        float l0 = v0 - __uint_as_float(h01 << 16);
        float l1 = v1 - __uint_as_float(h01 & 0xFFFF0000u);
        float l2 = v2 - __uint_as_float(h23 << 16);
        float l3 = v3 - __uint_as_float(h23 & 0xFFFF0000u);
        u32 lo01 = cvt_pk_bf16(l0, l1);
        u32 lo23 = cvt_pk_bf16(l2, l3);
        *reinterpret_cast<uint2*>(&lo[row * LO_STRIDE + nb]) = make_uint2(lo01, lo23);
      }
    }
  }
  __syncthreads();
}

// ---------------------------------------------------------------------------
// Main fused kernel. Block b = ray b; row = sample index (0..63); 512 threads.
// ---------------------------------------------------------------------------
__global__ __launch_bounds__(512, 4)
void nerf_kernel(const float* __restrict__ xyz, const float* __restrict__ vdirs,
                 const float* __restrict__ b1, const float* __restrict__ b2,
                 const float* __restrict__ b3, const float* __restrict__ wsig,
                 const float* __restrict__ bsig, const float* __restrict__ bfeat,
                 const float* __restrict__ bdir, const float* __restrict__ wrgb,
                 const float* __restrict__ brgb, float* __restrict__ out) {
  __shared__ u16  s_hi[NROW * HI_STRIDE];   // 37888 B
  __shared__ u16  s_lo[NROW * LO_STRIDE];   // 33792 B
  __shared__ float s_geo[6];                // xyz[3], normalized vd[3]
  __shared__ float s_de[32];                // dir posenc (27) + zero pad

  const int tid  = threadIdx.x;
  const int wave = tid >> 6;
  const int lane = tid & 63;
  const int rg   = wave >> 2;               // row-group 0..1
  const int cg   = wave & 3;                // col-group 0..3

  // --- Phase A1: ray geometry (1 thread) ---
  if (tid == 0) {
    int rgI = blockIdx.x;
    float vx = vdirs[rgI * 3 + 0];
    float vy = vdirs[rgI * 3 + 1];
    float vz = vdirs[rgI * 3 + 2];
    float inv = 1.0f / sqrtf(vx * vx + vy * vy + vz * vz + 1e-20f);
    s_geo[0] = xyz[rgI * 3 + 0];
    s_geo[1] = xyz[rgI * 3 + 1];
    s_geo[2] = xyz[rgI * 3 + 2];
    s_geo[3] = vx * inv;
    s_geo[4] = vy * inv;
    s_geo[5] = vz * inv;
  }
  __syncthreads();

  // --- Phase A2: direction posenc (32 threads), 27 feats + zero pad ---
  if (tid < 32) {
    float val = 0.0f;
    if (tid < 3) val = s_geo[3 + tid];
    else if (tid < 27) {
      int fi = tid - 3, l = fi / 6, m = fi % 6;
      int ii = (m < 3) ? m : m - 3;
      float ang = s_geo[3 + ii] * (float)(1 << l);
      val = (m < 3) ? sinf(ang) : cosf(ang);
    }
    s_de[tid] = val;
  }

  // --- Phase B: sample points + posenc(L=10) -> cols 0..63 (63 zero), split ---
  {
    int row = tid >> 3, c8 = tid & 7;
    float t  = (float)row * (1.0f / 63.0f);
    float ts = 2.0f * (1.0f - t) + 6.0f * t;
    float p[3];
    p[0] = s_geo[0] + ts * s_geo[3];
    p[1] = s_geo[1] + ts * s_geo[4];
    p[2] = s_geo[2] + ts * s_geo[5];
    float val[8];
#pragma unroll
    for (int j = 0; j < 8; ++j) {
      int f = c8 * 8 + j;
      if (f < 3) val[j] = p[f];
      else if (f == 63) val[j] = 0.0f;
      else {
        int fi = f - 3, l = fi / 6, m = fi % 6;
        int ii = (m < 3) ? m : m - 3;
        float ang = p[ii] * (float)(1 << l);
        val[j] = (m < 3) ? sinf(ang) : cosf(ang);
      }
    }
    u32* hp = reinterpret_cast<u32*>(&s_hi[row * HI_STRIDE + c8 * 8]);
    u32* lp = reinterpret_cast<u32*>(&s_lo[row * LO_STRIDE + c8 * 8]);
#pragma unroll
    for (int jp = 0; jp < 4; ++jp) {
      u32 h = cvt_pk_bf16(val[2 * jp], val[2 * jp + 1]);
      float l0 = val[2 * jp]     - __uint_as_float(h << 16);
      float l1 = val[2 * jp + 1] - __uint_as_float(h & 0xFFFF0000u);
      hp[jp] = h;
      lp[jp] = cvt_pk_bf16(l0, l1);
    }
  }
  __syncthreads();

  // --- MLP trunk (split precision) ---
  mlp_layer<2, 4, 2, true, true>(s_hi, s_lo, g_whi + OFF_W1, g_wlo + OFF_W1,
                                 b1, rg, cg, lane);   // 63(+1)->256
  mlp_layer<8, 4, 2, true, true>(s_hi, s_lo, g_whi + OFF_W2, g_wlo + OFF_W2,
                                 b2, rg, cg, lane);   // 256->256
  mlp_layer<8, 4, 2, true, true>(s_hi, s_lo, g_whi + OFF_W3, g_wlo + OFF_W3,
                                 b3, rg, cg, lane);   // 256->256

  // --- sigma head (fp32 weights, split h3): reads before feat writeback ---
  float my_den = 0.0f;
  if (tid < 64) {
    float a = 0.0f;
    const float4* wp = reinterpret_cast<const float4*>(wsig);
#pragma unroll 8
    for (int k4 = 0; k4 < 64; ++k4) {
      U16x4 h = *reinterpret_cast<const U16x4*>(&s_hi[tid * HI_STRIDE + k4 * 4]);
      U16x4 l = *reinterpret_cast<const U16x4*>(&s_lo[tid * LO_STRIDE + k4 * 4]);
      float4 w = wp[k4];
      a += (bf2f(h.x) + bf2f(l.x)) * w.x + (bf2f(h.y) + bf2f(l.y)) * w.y
         + (bf2f(h.z) + bf2f(l.z)) * w.z + (bf2f(h.w) + bf2f(l.w)) * w.w;
    }
    my_den = wash(a + bsig[0]);
  }
  // ordering safe: feat layer's internal __syncthreads precedes its writes

  mlp_layer<8, 4, 2, false, false>(s_hi, s_lo, g_whi + OFF_WF, g_wlo,
                                   bfeat, rg, cg, lane); // feat (bf16, no relu)

  // --- append direction encoding: cols 256..287 (283..287 zero via s_de pad) ---
  {
    int row = tid >> 3, i0 = (tid & 7) * 4;
    u32 d01 = cvt_pk_bf16(s_de[i0 + 0], s_de[i0 + 1]);
    u32 d23 = cvt_pk_bf16(s_de[i0 + 2], s_de[i0 + 3]);
    u32* dp = reinterpret_cast<u32*>(&s_hi[row * HI_STRIDE + 256 + i0]);
    dp[0] = d01; dp[1] = d23;
  }
  __syncthreads();

  mlp_layer<9, 2, 2, true, false>(s_hi, s_lo, g_whi + OFF_WD, g_wlo,
                                  bdir, rg, cg, lane);  // 283(+5)->128

  // --- rgb head (fp32 weights) ---
  float r0 = 0.0f, r1 = 0.0f, r2 = 0.0f;
  if (tid < 64) {
    float a0 = brgb[0], a1 = brgb[1], a2 = brgb[2];
#pragma unroll 8
    for (int k = 0; k < 128; ++k) {
      float hv = bf2f(s_hi[tid * HI_STRIDE + k]);
      a0 += hv * wrgb[k * 3 + 0];
      a1 += hv * wrgb[k * 3 + 1];
      a2 += hv * wrgb[k * 3 + 2];
    }
    a0 = wash(a0); a1 = wash(a1); a2 = wash(a2);
    r0 = 1.0f / (1.0f + expf(-a0));
    r1 = 1.0f / (1.0f + expf(-a1));
    r2 = 1.0f / (1.0f + expf(-a2));
  }

  // --- Phase D: volume render (wave 0; lane = sample) ---
  if (wave == 0) {
    int rgI = blockIdx.x;
    float t  = (float)lane * (1.0f / 63.0f);
    float ts = 2.0f * (1.0f - t) + 6.0f * t;
    float delta;
    if (lane < 63) {
      float t2 = (float)(lane + 1) * (1.0f / 63.0f);
      delta = (2.0f * (1.0f - t2) + 6.0f * t2) - ts;
    } else delta = 1e10f;
    float sig = fmaxf(my_den, 0.0f);
    float sd  = fminf(sig * delta, 60.0f);   // exp(-60)~1e-26: same semantics
    // exclusive prefix sum of sd across the 64-lane wave
    float incl = sd;
#pragma unroll
    for (int o = 1; o < 64; o <<= 1) {
      float v = __shfl_up(incl, o, 64);
      if (lane >= o) incl += v;
    }
    float excl  = fminf(fmaxf(incl - sd, 0.0f), 60.0f);
    float T     = expf(-excl);
    float alpha = 1.0f - expf(-sd);
    float w     = T * alpha;
    float sw = w, swr = w * r0, swg = w * r1, swb = w * r2, swd = w * ts;
#pragma unroll
    for (int o = 32; o > 0; o >>= 1) {
      sw  += __shfl_xor(sw,  o, 64);
      swr += __shfl_xor(swr, o, 64);
      swg += __shfl_xor(swg, o, 64);
      swb += __shfl_xor(swb, o, 64);
      swd += __shfl_xor(swd, o, 64);
    }
    if (lane == 0) {
      float bg = 1.0f - sw;               // white background
      out[rgI * 3 + 0]  = swr + bg;
      out[rgI * 3 + 1]  = swg + bg;
      out[rgI * 3 + 2]  = swb + bg;
      out[12288 + rgI]  = swd;            // depth_map
      out[16384 + rgI]  = sw;             // alpha_map
    }
  }
}

extern "C" void kernel_launch(void* const* d_in, const int* in_sizes, int n_in,
                              void* d_out, int out_size, void* d_ws, size_t ws_size,
                              hipStream_t stream) {
  const float* xyz   = (const float*)d_in[0];
  const float* vdirs = (const float*)d_in[1];
  const float* W1    = (const float*)d_in[2];
  const float* b1    = (const float*)d_in[3];
  const float* W2    = (const float*)d_in[4];
  const float* b2    = (const float*)d_in[5];
  const float* W3    = (const float*)d_in[6];
  const float* b3    = (const float*)d_in[7];
  const float* Wsig  = (const float*)d_in[8];
  const float* bsig  = (const float*)d_in[9];
  const float* Wfeat = (const float*)d_in[10];
  const float* bfeat = (const float*)d_in[11];
  const float* Wdir  = (const float*)d_in[12];
  const float* bdir  = (const float*)d_in[13];
  const float* Wrgb  = (const float*)d_in[14];
  const float* brgb  = (const float*)d_in[15];
  float* out = (float*)d_out;

  repack_kernel<<<dim3(976), dim3(256), 0, stream>>>(W1, W2, W3, Wfeat, Wdir);
  nerf_kernel<<<dim3(4096), dim3(512), 0, stream>>>(
      xyz, vdirs, b1, b2, b3, Wsig, bsig, bfeat, bdir, Wrgb, brgb, out);
}

// Round 11
// 364.959 us; speedup vs baseline: 1.9543x; 1.0056x over previous
//
#include <hip/hip_runtime.h>
#include <hip/hip_bf16.h>
#include <math.h>

// NeRF coarse renderer, fused MFMA implementation with split-bf16 trunk.
// I/O dtype: FLOAT32. Density path (W1,W2,W3,sigma) runs in hi+lo split-bf16
// (~fp22 effective); rgb branch (Wfeat,Wdir,rgb) enters linearly -> bf16.
// Round 11 (base: R10 measured 327us, MfmaUtil 40, clean counters):
// parallelize the serial heads that expose barrier skew / tail idle time:
//  - sigma head: was 64 iters on wave 0 only (delays wave 0 into feat layer).
//    Now all 512 threads compute 8-part partials into s_part[8][64]; wave 0
//    reduces at render time. fp32 reassociation only (~1e-6 rel).
//  - rgb head: was 128 scalar-LDS iters on 64 threads with 7 waves idle.
//    Now 3 waves (one per channel), U16x4-vectorized (32 LDS reads), channel
//    k-order preserved -> bit-identical rgb. Handoff via s_rgb (stride 3,
//    conflict-free) + one barrier.
// Trunk (full k-unroll + term-major MFMA + setprio + packed cvt writeback)
// unchanged from the measured R10 kernel.
// LDS 75008 B -> still 2 blocks/CU. Block = 1 ray = 64 samples; 512 threads.

typedef unsigned short u16;
typedef unsigned int   u32;
typedef __bf16 bf16x8 __attribute__((ext_vector_type(8)));
typedef float  f32x4  __attribute__((ext_vector_type(4)));

#define HI_STRIDE 296   // u16 elems; 592B rows -> conflict-free b128 (20i%32 pattern)
#define LO_STRIDE 264   // u16 elems; 528B rows -> conflict-free b128 (4i%32 pattern)
#define NROW 64

// Repacked weights (MFMA A-operand fragments):
// hi: W1(16384) W2(65536) W3(65536) Wfeat(65536) Wdir(36864)
// lo: W1(16384) W2(65536) W3(65536)   (residuals, trunk only)
__device__ __align__(16) u16 g_whi[249856];
__device__ __align__(16) u16 g_wlo[147456];

constexpr int OFF_W1 = 0;
constexpr int OFF_W2 = 16384;
constexpr int OFF_W3 = 81920;
constexpr int OFF_WF = 147456;
constexpr int OFF_WD = 212992;

static __device__ __forceinline__ float bf2f(u16 u) {
  return __uint_as_float(((u32)u) << 16);
}
static __device__ __forceinline__ u16 f2bf(float f) {   // RNE (repack kernel only)
  u32 x = __float_as_uint(f);
  return (u16)((x + 0x7FFFu + ((x >> 16) & 1u)) >> 16);
}
// Packed f32x2 -> bf16x2 (RNE). dst.lo16 = bf(a), dst.hi16 = bf(b).
static __device__ __forceinline__ u32 cvt_pk_bf16(float a, float b) {
  u32 r;
  asm("v_cvt_pk_bf16_f32 %0, %1, %2" : "=v"(r) : "v"(a), "v"(b));
  return r;
}
static __device__ __forceinline__ float wash(float x) { // NaN -> 0
  return (x == x) ? x : 0.0f;
}

struct alignas(8) U16x4 { u16 x, y, z, w; };

// ---------------------------------------------------------------------------
// Weight repack (f32 -> bf16 hi, + bf16 lo residual for W1..W3) into
// A-operand fragments of mfma_f32_16x16x32_bf16 (A := W^T tile):
// element pos = lane*8 + j of fragment (t,s) holds
//   W[s*32 + (lane>>4)*8 + j][t*16 + (lane&15)]   (zero-padded for k >= K).
// One pass: e < 249856; trunk range also emits the lo residual.
// ---------------------------------------------------------------------------
__global__ void repack_kernel(const float* __restrict__ w1, const float* __restrict__ w2,
                              const float* __restrict__ w3, const float* __restrict__ wf,
                              const float* __restrict__ wd) {
  int e = blockIdx.x * 256 + threadIdx.x;
  const float* src; int K, N, ks, base;
  if (e < 81920)       { if (e < 16384) { src = w1; K = 63;  N = 256; ks = 2; base = OFF_W1; }
                         else           { src = w2; K = 256; N = 256; ks = 8; base = OFF_W2; } }
  else if (e < 147456) { src = w3; K = 256; N = 256; ks = 8; base = OFF_W3; }
  else if (e < 212992) { src = wf; K = 256; N = 256; ks = 8; base = OFF_WF; }
  else                 { src = wd; K = 283; N = 128; ks = 9; base = OFF_WD; }
  int le   = e - base;
  int f    = le >> 9, pos = le & 511;
  int lane = pos >> 3, j = pos & 7;
  int t    = f / ks,  s = f - t * ks;
  int k    = s * 32 + ((lane >> 4) << 3) + j;
  int n    = (t << 4) + (lane & 15);
  float v  = (k < K) ? src[k * N + n] : 0.0f;
  u16 h    = f2bf(v);
  g_whi[e] = h;
  if (e < 147456) g_wlo[e] = f2bf(v - bf2f(h));   // trunk residual plane
}

// ---------------------------------------------------------------------------
// One dense layer on the shared activation buffer, in place.
// 8 waves = 2 row-groups (rg) x 4 col-groups (cg). Wave computes RT row-tiles
// x NT col-tiles. SPLIT: acc += Wh*Ah + Wh*Al + Wl*Ah (fp32 accumulate);
// writeback stores hi + lo residual planes (packed cvt).
// k-loop fully unrolled (compile-time indices, SSA-clean); per k-step the
// fragments load then term-major MFMA (hh* then hl* then lh*) so consecutive
// MFMAs hit different acc tiles; setprio(1) keeps the matrix pipe fed while
// the other resident block issues memory ops.
// ---------------------------------------------------------------------------
template<int KS, int NT, int RT, bool RELU, bool SPLIT>
static __device__ __forceinline__ void mlp_layer(u16* hi, u16* lo,
                                                 const u16* __restrict__ wh_,
                                                 const u16* __restrict__ wl_,
                                                 const float* __restrict__ bias,
                                                 int rg, int cg, int lane) {
  f32x4 acc[RT][NT];
#pragma unroll
  for (int rt = 0; rt < RT; ++rt)
#pragma unroll
    for (int nt = 0; nt < NT; ++nt) {
      f32x4 z = {0.0f, 0.0f, 0.0f, 0.0f};
      acc[rt][nt] = z;
    }
  const int l15 = lane & 15, q = lane >> 4;
#pragma unroll
  for (int s = 0; s < KS; ++s) {
    bf16x8 ah[RT], al[RT];
#pragma unroll
    for (int rt = 0; rt < RT; ++rt) {
      const int row = (rg * RT + rt) * 16 + l15;
      ah[rt] = *reinterpret_cast<const bf16x8*>(&hi[row * HI_STRIDE + s * 32 + q * 8]);
      if (SPLIT)
        al[rt] = *reinterpret_cast<const bf16x8*>(&lo[row * LO_STRIDE + s * 32 + q * 8]);
    }
    bf16x8 wh[NT], wl[NT];
#pragma unroll
    for (int nt = 0; nt < NT; ++nt) {
      const int t = cg * NT + nt;
      wh[nt] = *reinterpret_cast<const bf16x8*>(&wh_[(t * KS + s) * 512 + lane * 8]);
      if (SPLIT)
        wl[nt] = *reinterpret_cast<const bf16x8*>(&wl_[(t * KS + s) * 512 + lane * 8]);
    }
    __builtin_amdgcn_s_setprio(1);
    // term hh: Wh * Ah (all tiles)
#pragma unroll
    for (int nt = 0; nt < NT; ++nt)
#pragma unroll
      for (int rt = 0; rt < RT; ++rt)
        acc[rt][nt] = __builtin_amdgcn_mfma_f32_16x16x32_bf16(
            wh[nt], ah[rt], acc[rt][nt], 0, 0, 0);
    if (SPLIT) {
      // term hl: Wh * Al
#pragma unroll
      for (int nt = 0; nt < NT; ++nt)
#pragma unroll
        for (int rt = 0; rt < RT; ++rt)
          acc[rt][nt] = __builtin_amdgcn_mfma_f32_16x16x32_bf16(
              wh[nt], al[rt], acc[rt][nt], 0, 0, 0);
      // term lh: Wl * Ah
#pragma unroll
      for (int nt = 0; nt < NT; ++nt)
#pragma unroll
        for (int rt = 0; rt < RT; ++rt)
          acc[rt][nt] = __builtin_amdgcn_mfma_f32_16x16x32_bf16(
              wl[nt], ah[rt], acc[rt][nt], 0, 0, 0);
    }
    __builtin_amdgcn_s_setprio(0);
  }
  __syncthreads();   // all reads of act complete before overwrite
#pragma unroll
  for (int nt = 0; nt < NT; ++nt) {
    const int nb = (cg * NT + nt) * 16 + q * 4;
    const float b0 = bias[nb + 0], b1 = bias[nb + 1];
    const float b2 = bias[nb + 2], b3 = bias[nb + 3];
#pragma unroll
    for (int rt = 0; rt < RT; ++rt) {
      const int row = (rg * RT + rt) * 16 + l15;
      float v0 = acc[rt][nt][0] + b0;
      float v1 = acc[rt][nt][1] + b1;
      float v2 = acc[rt][nt][2] + b2;
      float v3 = acc[rt][nt][3] + b3;
      if (RELU) {
        v0 = fmaxf(v0, 0.0f); v1 = fmaxf(v1, 0.0f);
        v2 = fmaxf(v2, 0.0f); v3 = fmaxf(v3, 0.0f);
      }
      u32 h01 = cvt_pk_bf16(v0, v1);
      u32 h23 = cvt_pk_bf16(v2, v3);
      *reinterpret_cast<uint2*>(&hi[row * HI_STRIDE + nb]) = make_uint2(h01, h23);
      if (SPLIT) {
        float l0 = v0 - __uint_as_float(h01 << 16);
        float l1 = v1 - __uint_as_float(h01 & 0xFFFF0000u);
        float l2 = v2 - __uint_as_float(h23 << 16);
        float l3 = v3 - __uint_as_float(h23 & 0xFFFF0000u);
        u32 lo01 = cvt_pk_bf16(l0, l1);
        u32 lo23 = cvt_pk_bf16(l2, l3);
        *reinterpret_cast<uint2*>(&lo[row * LO_STRIDE + nb]) = make_uint2(lo01, lo23);
      }
    }
  }
  __syncthreads();
}

// ---------------------------------------------------------------------------
// Main fused kernel. Block b = ray b; row = sample index (0..63); 512 threads.
// ---------------------------------------------------------------------------
__global__ __launch_bounds__(512, 4)
void nerf_kernel(const float* __restrict__ xyz, const float* __restrict__ vdirs,
                 const float* __restrict__ b1, const float* __restrict__ b2,
                 const float* __restrict__ b3, const float* __restrict__ wsig,
                 const float* __restrict__ bsig, const float* __restrict__ bfeat,
                 const float* __restrict__ bdir, const float* __restrict__ wrgb,
                 const float* __restrict__ brgb, float* __restrict__ out) {
  __shared__ u16  s_hi[NROW * HI_STRIDE];   // 37888 B
  __shared__ u16  s_lo[NROW * LO_STRIDE];   // 33792 B
  __shared__ float s_geo[6];                // xyz[3], normalized vd[3]
  __shared__ float s_de[32];                // dir posenc (27) + zero pad
  __shared__ float s_part[512];             // sigma partials [part 0..7][row 0..63]
  __shared__ float s_rgb[192];              // rgb per row, stride 3 (bank-clean)

  const int tid  = threadIdx.x;
  const int wave = tid >> 6;
  const int lane = tid & 63;
  const int rg   = wave >> 2;               // row-group 0..1
  const int cg   = wave & 3;                // col-group 0..3

  // --- Phase A1: ray geometry (1 thread) ---
  if (tid == 0) {
    int rgI = blockIdx.x;
    float vx = vdirs[rgI * 3 + 0];
    float vy = vdirs[rgI * 3 + 1];
    float vz = vdirs[rgI * 3 + 2];
    float inv = 1.0f / sqrtf(vx * vx + vy * vy + vz * vz + 1e-20f);
    s_geo[0] = xyz[rgI * 3 + 0];
    s_geo[1] = xyz[rgI * 3 + 1];
    s_geo[2] = xyz[rgI * 3 + 2];
    s_geo[3] = vx * inv;
    s_geo[4] = vy * inv;
    s_geo[5] = vz * inv;
  }
  __syncthreads();

  // --- Phase A2: direction posenc (32 threads), 27 feats + zero pad ---
  if (tid < 32) {
    float val = 0.0f;
    if (tid < 3) val = s_geo[3 + tid];
    else if (tid < 27) {
      int fi = tid - 3, l = fi / 6, m = fi % 6;
      int ii = (m < 3) ? m : m - 3;
      float ang = s_geo[3 + ii] * (float)(1 << l);
      val = (m < 3) ? sinf(ang) : cosf(ang);
    }
    s_de[tid] = val;
  }

  // --- Phase B: sample points + posenc(L=10) -> cols 0..63 (63 zero), split ---
  {
    int row = tid >> 3, c8 = tid & 7;
    float t  = (float)row * (1.0f / 63.0f);
    float ts = 2.0f * (1.0f - t) + 6.0f * t;
    float p[3];
    p[0] = s_geo[0] + ts * s_geo[3];
    p[1] = s_geo[1] + ts * s_geo[4];
    p[2] = s_geo[2] + ts * s_geo[5];
    float val[8];
#pragma unroll
    for (int j = 0; j < 8; ++j) {
      int f = c8 * 8 + j;
      if (f < 3) val[j] = p[f];
      else if (f == 63) val[j] = 0.0f;
      else {
        int fi = f - 3, l = fi / 6, m = fi % 6;
        int ii = (m < 3) ? m : m - 3;
        float ang = p[ii] * (float)(1 << l);
        val[j] = (m < 3) ? sinf(ang) : cosf(ang);
      }
    }
    u32* hp = reinterpret_cast<u32*>(&s_hi[row * HI_STRIDE + c8 * 8]);
    u32* lp = reinterpret_cast<u32*>(&s_lo[row * LO_STRIDE + c8 * 8]);
#pragma unroll
    for (int jp = 0; jp < 4; ++jp) {
      u32 h = cvt_pk_bf16(val[2 * jp], val[2 * jp + 1]);
      float l0 = val[2 * jp]     - __uint_as_float(h << 16);
      float l1 = val[2 * jp + 1] - __uint_as_float(h & 0xFFFF0000u);
      hp[jp] = h;
      lp[jp] = cvt_pk_bf16(l0, l1);
    }
  }
  __syncthreads();

  // --- MLP trunk (split precision) ---
  mlp_layer<2, 4, 2, true, true>(s_hi, s_lo, g_whi + OFF_W1, g_wlo + OFF_W1,
                                 b1, rg, cg, lane);   // 63(+1)->256
  mlp_layer<8, 4, 2, true, true>(s_hi, s_lo, g_whi + OFF_W2, g_wlo + OFF_W2,
                                 b2, rg, cg, lane);   // 256->256
  mlp_layer<8, 4, 2, true, true>(s_hi, s_lo, g_whi + OFF_W3, g_wlo + OFF_W3,
                                 b3, rg, cg, lane);   // 256->256

  // --- sigma head partials: ALL 512 threads (part = wave, row = lane) ---
  // Reads h3 (split) before the feat layer's internal barrier -> ordering
  // safe vs the feat writeback. Wave 0 reduces the 8 partials in phase D.
  {
    const int row = lane, part = wave;
    float a = 0.0f;
    const float4* wp = reinterpret_cast<const float4*>(wsig);
#pragma unroll
    for (int i = 0; i < 8; ++i) {
      int k4 = part * 8 + i;
      U16x4 h = *reinterpret_cast<const U16x4*>(&s_hi[row * HI_STRIDE + k4 * 4]);
      U16x4 l = *reinterpret_cast<const U16x4*>(&s_lo[row * LO_STRIDE + k4 * 4]);
      float4 w = wp[k4];
      a += (bf2f(h.x) + bf2f(l.x)) * w.x + (bf2f(h.y) + bf2f(l.y)) * w.y
         + (bf2f(h.z) + bf2f(l.z)) * w.z + (bf2f(h.w) + bf2f(l.w)) * w.w;
    }
    s_part[part * 64 + row] = a;
  }

  mlp_layer<8, 4, 2, false, false>(s_hi, s_lo, g_whi + OFF_WF, g_wlo,
                                   bfeat, rg, cg, lane); // feat (bf16, no relu)

  // --- append direction encoding: cols 256..287 (283..287 zero via s_de pad) ---
  {
    int row = tid >> 3, i0 = (tid & 7) * 4;
    u32 d01 = cvt_pk_bf16(s_de[i0 + 0], s_de[i0 + 1]);
    u32 d23 = cvt_pk_bf16(s_de[i0 + 2], s_de[i0 + 3]);
    u32* dp = reinterpret_cast<u32*>(&s_hi[row * HI_STRIDE + 256 + i0]);
    dp[0] = d01; dp[1] = d23;
  }
  __syncthreads();

  mlp_layer<9, 2, 2, true, false>(s_hi, s_lo, g_whi + OFF_WD, g_wlo,
                                  bdir, rg, cg, lane);  // 283(+5)->128

  // --- rgb head: waves 0-2, one color channel per wave, row = lane ---
  // Per-channel k-order identical to the old serial loop -> bit-identical.
  if (tid < 192) {
    const int c = wave, r = lane;
    float a = brgb[c];
#pragma unroll 8
    for (int k4 = 0; k4 < 32; ++k4) {
      U16x4 h = *reinterpret_cast<const U16x4*>(&s_hi[r * HI_STRIDE + k4 * 4]);
      a += bf2f(h.x) * wrgb[(k4 * 4 + 0) * 3 + c];
      a += bf2f(h.y) * wrgb[(k4 * 4 + 1) * 3 + c];
      a += bf2f(h.z) * wrgb[(k4 * 4 + 2) * 3 + c];
      a += bf2f(h.w) * wrgb[(k4 * 4 + 3) * 3 + c];
    }
    a = wash(a);
    s_rgb[r * 3 + c] = 1.0f / (1.0f + expf(-a));
  }
  __syncthreads();   // s_rgb (and long-written s_part) visible to wave 0

  // --- Phase D: volume render (wave 0; lane = sample) ---
  if (wave == 0) {
    int rgI = blockIdx.x;
    // reduce sigma partials (p ascending, deterministic)
    float den = 0.0f;
#pragma unroll
    for (int p = 0; p < 8; ++p) den += s_part[p * 64 + lane];
    float my_den = wash(den + bsig[0]);
    float r0 = s_rgb[lane * 3 + 0];
    float r1 = s_rgb[lane * 3 + 1];
    float r2 = s_rgb[lane * 3 + 2];

    float t  = (float)lane * (1.0f / 63.0f);
    float ts = 2.0f * (1.0f - t) + 6.0f * t;
    float delta;
    if (lane < 63) {
      float t2 = (float)(lane + 1) * (1.0f / 63.0f);
      delta = (2.0f * (1.0f - t2) + 6.0f * t2) - ts;
    } else delta = 1e10f;
    float sig = fmaxf(my_den, 0.0f);
    float sd  = fminf(sig * delta, 60.0f);   // exp(-60)~1e-26: same semantics
    // exclusive prefix sum of sd across the 64-lane wave
    float incl = sd;
#pragma unroll
    for (int o = 1; o < 64; o <<= 1) {
      float v = __shfl_up(incl, o, 64);
      if (lane >= o) incl += v;
    }
    float excl  = fminf(fmaxf(incl - sd, 0.0f), 60.0f);
    float T     = expf(-excl);
    float alpha = 1.0f - expf(-sd);
    float w     = T * alpha;
    float sw = w, swr = w * r0, swg = w * r1, swb = w * r2, swd = w * ts;
#pragma unroll
    for (int o = 32; o > 0; o >>= 1) {
      sw  += __shfl_xor(sw,  o, 64);
      swr += __shfl_xor(swr, o, 64);
      swg += __shfl_xor(swg, o, 64);
      swb += __shfl_xor(swb, o, 64);
      swd += __shfl_xor(swd, o, 64);
    }
    if (lane == 0) {
      float bg = 1.0f - sw;               // white background
      out[rgI * 3 + 0]  = swr + bg;
      out[rgI * 3 + 1]  = swg + bg;
      out[rgI * 3 + 2]  = swb + bg;
      out[12288 + rgI]  = swd;            // depth_map
      out[16384 + rgI]  = sw;             // alpha_map
    }
  }
}

extern "C" void kernel_launch(void* const* d_in, const int* in_sizes, int n_in,
                              void* d_out, int out_size, void* d_ws, size_t ws_size,
                              hipStream_t stream) {
  const float* xyz   = (const float*)d_in[0];
  const float* vdirs = (const float*)d_in[1];
  const float* W1    = (const float*)d_in[2];
  const float* b1    = (const float*)d_in[3];
  const float* W2    = (const float*)d_in[4];
  const float* b2    = (const float*)d_in[5];
  const float* W3    = (const float*)d_in[6];
  const float* b3    = (const float*)d_in[7];
  const float* Wsig  = (const float*)d_in[8];
  const float* bsig  = (const float*)d_in[9];
  const float* Wfeat = (const float*)d_in[10];
  const float* bfeat = (const float*)d_in[11];
  const float* Wdir  = (const float*)d_in[12];
  const float* bdir  = (const float*)d_in[13];
  const float* Wrgb  = (const float*)d_in[14];
  const float* brgb  = (const float*)d_in[15];
  float* out = (float*)d_out;

  repack_kernel<<<dim3(976), dim3(256), 0, stream>>>(W1, W2, W3, Wfeat, Wdir);
  nerf_kernel<<<dim3(4096), dim3(512), 0, stream>>>(
      xyz, vdirs, b1, b2, b3, Wsig, bsig, bfeat, bdir, Wrgb, brgb, out);
}